// Round 2
// baseline (610.158 us; speedup 1.0000x reference)
//
#include <hip/hip_runtime.h>
#include <math.h>

// n=16384 Gaussian points in 3D. Exact 12-NN (incl self) via x-bin-sorted
// window scan, then closed-form GCNConv + mean:
//   out[i] = b + ( (W·p_i)·(1 + 11/sqrt(2)) + 0.5 * sum_{11NN} W·|p_i - p_j| ) / 12
//
// Pipeline: K1 histogram(x) -> K2 prefix scan -> K3 scatter into bin-sorted
// float4 array (x,y,z,orig_idx) -> K4 query.
// K4: 8 lanes/query scan outward (strided) from the query's sorted position,
// branch-free med3 top-12 per lane; stop when ((|dx|-BW)^2 > group-min of
// per-lane 12th) — exact bound since bins are monotone in x. Leader merges
// 8 sorted lists -> exact tau; phase 2 rescans window, accumulates W·|diff|
// for d2 <= tau (self term is 0).

#define NBINS   2048
#define XMIN_   (-6.0f)
#define XRANGE_ (12.0f)
#define BW_     (XRANGE_ / (float)NBINS)
#define INVBW_  ((float)NBINS / XRANGE_)
#define GL      8                 // lanes per query
#define QPB     32                // queries per block (256/8)
#define KK      12
#define BIG     3.0e38f

__device__ __forceinline__ int bin_of(float x) {
  int b = (int)((x - XMIN_) * INVBW_);
  b = b < 0 ? 0 : b;
  b = b > NBINS - 1 ? NBINS - 1 : b;
  return b;
}

__device__ __forceinline__ float d2_of(float dx, float dy, float dz) {
  return fmaf(dx, dx, fmaf(dy, dy, dz * dz));
}

// ---------------- K1: histogram ----------------
__global__ void hist_kernel(const float* __restrict__ p, int* __restrict__ hist, int n) {
  const int i = blockIdx.x * blockDim.x + threadIdx.x;
  if (i < n) {
    atomicAdd(&hist[bin_of(p[3 * i])], 1);
  }
}

// ---------------- K2: exclusive prefix scan (1 block, 256 thr, 8 bins/thr) ---
__global__ __launch_bounds__(256)
void scan_kernel(const int* __restrict__ hist, int* __restrict__ cursor) {
  __shared__ int s[256];
  const int tid = threadIdx.x;
  const int base = tid * (NBINS / 256);
  int v[NBINS / 256];
  int sum = 0;
#pragma unroll
  for (int t = 0; t < NBINS / 256; ++t) { v[t] = hist[base + t]; sum += v[t]; }
  s[tid] = sum;
  __syncthreads();
#pragma unroll
  for (int off = 1; off < 256; off <<= 1) {
    int x = (tid >= off) ? s[tid - off] : 0;
    __syncthreads();
    s[tid] += x;
    __syncthreads();
  }
  int run = (tid > 0) ? s[tid - 1] : 0;
#pragma unroll
  for (int t = 0; t < NBINS / 256; ++t) { cursor[base + t] = run; run += v[t]; }
}

// ---------------- K3: scatter into bin-sorted array --------------------------
__global__ void scatter_kernel(const float* __restrict__ p, int* __restrict__ cursor,
                               float4* __restrict__ sorted, int n) {
  const int i = blockIdx.x * blockDim.x + threadIdx.x;
  if (i < n) {
    const float x = p[3 * i + 0];
    const float y = p[3 * i + 1];
    const float z = p[3 * i + 2];
    const int b = bin_of(x);
    const int pos = atomicAdd(&cursor[b], 1);
    sorted[pos] = make_float4(x, y, z, __int_as_float(i));
  }
}

// ---------------- K4: query ---------------------------------------------------
__global__ __launch_bounds__(256)
void query_kernel(const float4* __restrict__ sv, const float* __restrict__ W,
                  const float* __restrict__ bias, float* __restrict__ out, int n) {
  __shared__ float s_d[256 * KK];
  __shared__ float s_tau[QPB];

  const int tid = threadIdx.x;
  const int l   = tid & (GL - 1);
  const int qg  = tid >> 3;
  const int t   = blockIdx.x * QPB + qg;      // sorted position of the query
  const float SLACK = BW_ * 1.02f;

  const float4 me = sv[t];
  const float xi = me.x, yi = me.y, zi = me.z;
  const int orig = __float_as_int(me.w);

  float dist[KK];
#pragma unroll
  for (int k = 0; k < KK; ++k) dist[k] = BIG;

  // ---- phase 1 right (lane 0 covers self at pos t) ----
  {
    int pos = t + l;
    while (true) {
      float x3 = 0.f; bool v3 = false;
#pragma unroll
      for (int e = 0; e < 4; ++e) {
        const int q = pos + 8 * e;
        const bool v = (q < n);
        const float4 c = sv[v ? q : 0];
        const float dx = xi - c.x, dy = yi - c.y, dz = zi - c.z;
        const float d2 = v ? d2_of(dx, dy, dz) : BIG;   // BIG insert is a no-op
#pragma unroll
        for (int k = KK - 1; k >= 1; --k)
          dist[k] = __builtin_amdgcn_fmed3f(d2, dist[k - 1], dist[k]);
        dist[0] = fminf(dist[0], d2);
        if (e == 3) { x3 = c.x; v3 = v; }
      }
      pos += 32;
      float tub = dist[KK - 1];
      tub = fminf(tub, __shfl_xor(tub, 1));
      tub = fminf(tub, __shfl_xor(tub, 2));
      tub = fminf(tub, __shfl_xor(tub, 4));
      const float m = (x3 - xi) - SLACK;
      int dn = (!v3 || (m > 0.f && m * m > tub)) ? 1 : 0;
      dn &= __shfl_xor(dn, 1);
      dn &= __shfl_xor(dn, 2);
      dn &= __shfl_xor(dn, 4);
      if (dn) break;
    }
  }
  // ---- phase 1 left ----
  {
    int pos = t - 1 - l;
    while (true) {
      float x3 = 0.f; bool v3 = false;
#pragma unroll
      for (int e = 0; e < 4; ++e) {
        const int q = pos - 8 * e;
        const bool v = (q >= 0);
        const float4 c = sv[v ? q : 0];
        const float dx = xi - c.x, dy = yi - c.y, dz = zi - c.z;
        const float d2 = v ? d2_of(dx, dy, dz) : BIG;
#pragma unroll
        for (int k = KK - 1; k >= 1; --k)
          dist[k] = __builtin_amdgcn_fmed3f(d2, dist[k - 1], dist[k]);
        dist[0] = fminf(dist[0], d2);
        if (e == 3) { x3 = c.x; v3 = v; }
      }
      pos -= 32;
      float tub = dist[KK - 1];
      tub = fminf(tub, __shfl_xor(tub, 1));
      tub = fminf(tub, __shfl_xor(tub, 2));
      tub = fminf(tub, __shfl_xor(tub, 4));
      const float m = (xi - x3) - SLACK;
      int dn = (!v3 || (m > 0.f && m * m > tub)) ? 1 : 0;
      dn &= __shfl_xor(dn, 1);
      dn &= __shfl_xor(dn, 2);
      dn &= __shfl_xor(dn, 4);
      if (dn) break;
    }
  }

  // ---- merge 8 sorted lists -> exact tau (12th smallest incl self) ----
#pragma unroll
  for (int k = 0; k < KK; ++k) s_d[tid * KK + k] = dist[k];
  __syncthreads();
  if (l == 0) {
    int h[GL];
#pragma unroll
    for (int g = 0; g < GL; ++g) h[g] = 0;
    float tau = 0.f;
    for (int r = 0; r < KK; ++r) {
      float best = 3.4e38f; int bs = 0;
#pragma unroll
      for (int g = 0; g < GL; ++g) {
        const float v = s_d[(tid + g) * KK + h[g]];
        if (v < best) { best = v; bs = g; }
      }
#pragma unroll
      for (int g = 0; g < GL; ++g) h[g] += (bs == g) ? 1 : 0;
      tau = best;
    }
    s_tau[qg] = tau;
  }
  __syncthreads();
  const float tau = s_tau[qg];
  const float W0 = W[0], W1 = W[1], W2 = W[2];

  // ---- phase 2: accumulate W·|diff| for d2 <= tau (per-lane exit OK) ----
  float acc = 0.f;
  {
    int pos = t + l;
    while (true) {
      float x3 = 0.f; bool v3 = false;
#pragma unroll
      for (int e = 0; e < 4; ++e) {
        const int q = pos + 8 * e;
        const bool v = (q < n);
        const float4 c = sv[v ? q : 0];
        const float dx = xi - c.x, dy = yi - c.y, dz = zi - c.z;
        const float d2 = v ? d2_of(dx, dy, dz) : BIG;
        if (d2 <= tau)
          acc += W0 * fabsf(dx) + W1 * fabsf(dy) + W2 * fabsf(dz);
        if (e == 3) { x3 = c.x; v3 = v; }
      }
      pos += 32;
      const float m = (x3 - xi) - SLACK;
      if (!v3 || (m > 0.f && m * m > tau)) break;
    }
  }
  {
    int pos = t - 1 - l;
    while (true) {
      float x3 = 0.f; bool v3 = false;
#pragma unroll
      for (int e = 0; e < 4; ++e) {
        const int q = pos - 8 * e;
        const bool v = (q >= 0);
        const float4 c = sv[v ? q : 0];
        const float dx = xi - c.x, dy = yi - c.y, dz = zi - c.z;
        const float d2 = v ? d2_of(dx, dy, dz) : BIG;
        if (d2 <= tau)
          acc += W0 * fabsf(dx) + W1 * fabsf(dy) + W2 * fabsf(dz);
        if (e == 3) { x3 = c.x; v3 = v; }
      }
      pos -= 32;
      const float m = (xi - x3) - SLACK;
      if (!v3 || (m > 0.f && m * m > tau)) break;
    }
  }

  // ---- reduce across the 8 lanes, lane 0 writes ----
  acc += __shfl_xor(acc, 1);
  acc += __shfl_xor(acc, 2);
  acc += __shfl_xor(acc, 4);
  if (l == 0) {
    const float xw0 = W0 * xi + W1 * yi + W2 * zi;
    // 1 + 11/sqrt(2)
    out[orig] = bias[0] + (xw0 * 8.778174593052022f + 0.5f * acc) * (1.0f / 12.0f);
  }
}

extern "C" void kernel_launch(void* const* d_in, const int* in_sizes, int n_in,
                              void* d_out, int out_size, void* d_ws, size_t ws_size,
                              hipStream_t stream) {
  const float* p  = (const float*)d_in[0];
  const float* W  = (const float*)d_in[1];
  const float* bb = (const float*)d_in[2];
  float* out = (float*)d_out;

  const int n = in_sizes[0] / 3;   // 16384

  // ws layout: hist [0,8K) | cursor [8K,16K) | sorted float4 [16K, 16K+16n)
  int*    hist   = (int*)d_ws;
  int*    cursor = (int*)((char*)d_ws + NBINS * 4);
  float4* sorted = (float4*)((char*)d_ws + 2 * NBINS * 4);

  hipMemsetAsync(hist, 0, NBINS * 4, stream);

  const int b256 = (n + 255) / 256;
  hist_kernel<<<b256, 256, 0, stream>>>(p, hist, n);
  scan_kernel<<<1, 256, 0, stream>>>(hist, cursor);
  scatter_kernel<<<b256, 256, 0, stream>>>(p, cursor, sorted, n);
  query_kernel<<<n / QPB, 256, 0, stream>>>(sorted, W, bb, out, n);
}

// Round 3
// 322.596 us; speedup vs baseline: 1.8914x; 1.8914x over previous
//
#include <hip/hip_runtime.h>
#include <math.h>

// n=16384 Gaussian points in 3D. Exact 12-NN (incl self) per point:
//   out[i] = b + ( (W·p_i)·(1 + 11/sqrt(2)) + 0.5 * sum_{11NN} W·|p_i - p_j| ) / 12
//
// R3: bin-sort by x (K1-K3), then K4 processes 32 CONSECUTIVE sorted queries
// per block with R1's throughput structure (LDS SoA tiles, float4 reads,
// branch-free med3 top-12, 8 slices/query), over an adaptive block-shared
// window that expands 512 positions/side/round until the 1D projection bound
//   (gap_x - binwidth)^2 > max_q(min_slice per-slice-12th)   [conservative]
// proves no outside point can be a 12-NN of any query in the block. Exact.
// Phase 2 rescans the final window with exact per-query tau (8-way merge).

#define NBINS   2048
#define XMIN_   (-6.0f)
#define XRANGE_ (12.0f)
#define BW_     (XRANGE_ / (float)NBINS)
#define INVBW_  ((float)NBINS / XRANGE_)
#define SLACK_  (BW_ * 1.02f)
#define TILE    1024
#define HALF    512
#define GL      8
#define QPB     32
#define KK      12
#define BIG     3.0e38f
#define PADX    1.0e30f

__device__ __forceinline__ int bin_of(float x) {
  int b = (int)((x - XMIN_) * INVBW_);
  b = b < 0 ? 0 : b;
  b = b > NBINS - 1 ? NBINS - 1 : b;
  return b;
}

// ---------------- K1: histogram ----------------
__global__ void hist_kernel(const float* __restrict__ p, int* __restrict__ hist, int n) {
  const int i = blockIdx.x * blockDim.x + threadIdx.x;
  if (i < n) atomicAdd(&hist[bin_of(p[3 * i])], 1);
}

// ---------------- K2: exclusive prefix scan ----------------
__global__ __launch_bounds__(256)
void scan_kernel(const int* __restrict__ hist, int* __restrict__ cursor) {
  __shared__ int s[256];
  const int tid = threadIdx.x;
  const int base = tid * (NBINS / 256);
  int v[NBINS / 256];
  int sum = 0;
#pragma unroll
  for (int t = 0; t < NBINS / 256; ++t) { v[t] = hist[base + t]; sum += v[t]; }
  s[tid] = sum;
  __syncthreads();
#pragma unroll
  for (int off = 1; off < 256; off <<= 1) {
    int x = (tid >= off) ? s[tid - off] : 0;
    __syncthreads();
    s[tid] += x;
    __syncthreads();
  }
  int run = (tid > 0) ? s[tid - 1] : 0;
#pragma unroll
  for (int t = 0; t < NBINS / 256; ++t) { cursor[base + t] = run; run += v[t]; }
}

// ---------------- K3: scatter into bin-sorted float4 array -------------------
__global__ void scatter_kernel(const float* __restrict__ p, int* __restrict__ cursor,
                               float4* __restrict__ sorted, int n) {
  const int i = blockIdx.x * blockDim.x + threadIdx.x;
  if (i < n) {
    const float x = p[3 * i + 0];
    const float y = p[3 * i + 1];
    const float z = p[3 * i + 2];
    const int pos = atomicAdd(&cursor[bin_of(x)], 1);
    sorted[pos] = make_float4(x, y, z, __int_as_float(i));
  }
}

// ---------------- K4: query ---------------------------------------------------
__global__ __launch_bounds__(256)
void query_kernel(const float4* __restrict__ sv, const float* __restrict__ W,
                  const float* __restrict__ bias, float* __restrict__ out, int n) {
  __shared__ __align__(16) float s_x[TILE];
  __shared__ __align__(16) float s_y[TILE];
  __shared__ __align__(16) float s_z[TILE];
  __shared__ float s_d[256 * KK];     // per-thread sorted lists (merge)
  __shared__ float s_red[256];        // tau_ub reduction scratch
  __shared__ float s_q[QPB];
  __shared__ float s_tau[QPB];
  __shared__ float s_xr[2];           // xmin, xmax of block queries
  __shared__ int   s_if[2];           // ldone, rdone

  const int tid = threadIdx.x;
  const int sl  = tid & (GL - 1);
  const int ql  = tid >> 3;
  const int c   = blockIdx.x * QPB + (QPB / 2);
  const int t   = blockIdx.x * QPB + ql;      // this query's sorted position

  const float4 me = sv[t];
  const float xi = me.x, yi = me.y, zi = me.z;
  const int orig = __float_as_int(me.w);

  // block query x-range
  if (sl == 0) s_q[ql] = xi;
  __syncthreads();
  if (tid == 0) {
    float mn = s_q[0], mx = s_q[0];
#pragma unroll
    for (int k = 1; k < QPB; ++k) { mn = fminf(mn, s_q[k]); mx = fmaxf(mx, s_q[k]); }
    s_xr[0] = mn; s_xr[1] = mx;
  }

  float dist[KK];
#pragma unroll
  for (int k = 0; k < KK; ++k) dist[k] = BIG;

  int rlo = c - HALF;                  // staged extent [rlo, rhi) (unclamped)
  int rhi = c + HALF;

  // stage round 0: [c-HALF, c+HALF) -> slots [0, TILE)
  __syncthreads();
#pragma unroll
  for (int j0 = 0; j0 < TILE; j0 += 256) {
    const int j = j0 + tid;
    const int pos = rlo + j;
    const bool v = (pos >= 0) && (pos < n);
    const float4 cc = v ? sv[pos] : make_float4(PADX, PADX, PADX, 0.f);
    s_x[j] = cc.x; s_y[j] = cc.y; s_z[j] = cc.z;
  }
  __syncthreads();

  for (;;) {
    // ---- eval tile: branch-free med3 top-12 insert, 4-candidate groups ----
#pragma unroll 2
    for (int g = sl; g < TILE / 4; g += GL) {
      const int cb = g * 4;
      const float4 X = *(const float4*)&s_x[cb];
      const float4 Y = *(const float4*)&s_y[cb];
      const float4 Z = *(const float4*)&s_z[cb];
      float d2v[4];
      { const float dx = xi - X.x, dy = yi - Y.x, dz = zi - Z.x; d2v[0] = dx*dx + dy*dy + dz*dz; }
      { const float dx = xi - X.y, dy = yi - Y.y, dz = zi - Z.y; d2v[1] = dx*dx + dy*dy + dz*dz; }
      { const float dx = xi - X.z, dy = yi - Y.z, dz = zi - Z.z; d2v[2] = dx*dx + dy*dy + dz*dz; }
      { const float dx = xi - X.w, dy = yi - Y.w, dz = zi - Z.w; d2v[3] = dx*dx + dy*dy + dz*dz; }
#pragma unroll
      for (int e = 0; e < 4; ++e) {
        const float d = d2v[e];
#pragma unroll
        for (int k = KK - 1; k >= 1; --k)
          dist[k] = __builtin_amdgcn_fmed3f(d, dist[k - 1], dist[k]);
        dist[0] = fminf(dist[0], d);
      }
    }

    // ---- block stop test ----
    s_red[tid] = dist[KK - 1];
    __syncthreads();
    if (tid < QPB) {
      float m = s_red[tid * GL];
#pragma unroll
      for (int g = 1; g < GL; ++g) m = fminf(m, s_red[tid * GL + g]);
      s_q[tid] = m;                    // per-query tau upper bound
    }
    __syncthreads();
    if (tid == 0) {
      float bt = s_q[0];
#pragma unroll
      for (int k = 1; k < QPB; ++k) bt = fmaxf(bt, s_q[k]);
      const float xmn = s_xr[0], xmx = s_xr[1];
      int ld = (rlo <= 0);
      if (!ld) {
        const float xl = sv[rlo].x;            // first staged left point
        const float g = xmn - xl - SLACK_;     // gap to any unstaged left point
        ld = (g > 0.f) && (g * g > bt);
      }
      int rd = (rhi >= n);
      if (!rd) {
        const float xr = sv[rhi - 1].x;        // last staged right point
        const float g = xr - SLACK_ - xmx;
        rd = (g > 0.f) && (g * g > bt);
      }
      s_if[0] = ld; s_if[1] = rd;
    }
    __syncthreads();
    const int ldone = s_if[0], rdone = s_if[1];
    if (ldone && rdone) break;

    // ---- stage next ring: left chunk -> [0,HALF), right chunk -> [HALF,TILE)
#pragma unroll
    for (int j0 = 0; j0 < HALF; j0 += 256) {
      const int j = j0 + tid;
      { // left
        const int pos = rlo - HALF + j;
        const bool v = (!ldone) && (pos >= 0) && (pos < n);
        const float4 cc = v ? sv[pos] : make_float4(PADX, PADX, PADX, 0.f);
        s_x[j] = cc.x; s_y[j] = cc.y; s_z[j] = cc.z;
      }
      { // right
        const int pos = rhi + j;
        const bool v = (!rdone) && (pos >= 0) && (pos < n);
        const float4 cc = v ? sv[pos] : make_float4(PADX, PADX, PADX, 0.f);
        s_x[HALF + j] = cc.x; s_y[HALF + j] = cc.y; s_z[HALF + j] = cc.z;
      }
    }
    if (!ldone) rlo -= HALF;
    if (!rdone) rhi += HALF;
    __syncthreads();
  }

  // ---- merge 8 sorted lists -> exact tau (12th smallest incl self) ----
  __syncthreads();
#pragma unroll
  for (int k = 0; k < KK; ++k) s_d[tid * KK + k] = dist[k];
  __syncthreads();
  if (sl == 0) {
    int h[GL];
#pragma unroll
    for (int g = 0; g < GL; ++g) h[g] = 0;
    float tau = 0.f;
    for (int r = 0; r < KK; ++r) {
      float best = 3.4e38f; int bs = 0;
#pragma unroll
      for (int g = 0; g < GL; ++g) {
        const float v = s_d[(tid + g) * KK + h[g]];
        if (v < best) { best = v; bs = g; }
      }
#pragma unroll
      for (int g = 0; g < GL; ++g) h[g] += (bs == g) ? 1 : 0;
      tau = best;
    }
    s_tau[ql] = tau;
  }
  __syncthreads();
  const float tau = s_tau[ql];
  const float W0 = W[0], W1 = W[1], W2 = W[2];

  // ---- phase 2: rescan final window, accumulate W·|diff| for d2 <= tau ----
  const int lo0 = rlo > 0 ? rlo : 0;
  const int hi0 = rhi < n ? rhi : n;
  float acc = 0.f;
  for (int s = lo0; s < hi0; s += TILE) {
    __syncthreads();
#pragma unroll
    for (int j0 = 0; j0 < TILE; j0 += 256) {
      const int j = j0 + tid;
      const int pos = s + j;
      const bool v = (pos < hi0);
      const float4 cc = v ? sv[pos] : make_float4(PADX, PADX, PADX, 0.f);
      s_x[j] = cc.x; s_y[j] = cc.y; s_z[j] = cc.z;
    }
    __syncthreads();
#pragma unroll 2
    for (int g = sl; g < TILE / 4; g += GL) {
      const int cb = g * 4;
      const float4 X = *(const float4*)&s_x[cb];
      const float4 Y = *(const float4*)&s_y[cb];
      const float4 Z = *(const float4*)&s_z[cb];
      {
        const float dx = xi - X.x, dy = yi - Y.x, dz = zi - Z.x;
        const float d2 = dx*dx + dy*dy + dz*dz;
        acc += (d2 <= tau) ? (W0 * fabsf(dx) + W1 * fabsf(dy) + W2 * fabsf(dz)) : 0.f;
      }
      {
        const float dx = xi - X.y, dy = yi - Y.y, dz = zi - Z.y;
        const float d2 = dx*dx + dy*dy + dz*dz;
        acc += (d2 <= tau) ? (W0 * fabsf(dx) + W1 * fabsf(dy) + W2 * fabsf(dz)) : 0.f;
      }
      {
        const float dx = xi - X.z, dy = yi - Y.z, dz = zi - Z.z;
        const float d2 = dx*dx + dy*dy + dz*dz;
        acc += (d2 <= tau) ? (W0 * fabsf(dx) + W1 * fabsf(dy) + W2 * fabsf(dz)) : 0.f;
      }
      {
        const float dx = xi - X.w, dy = yi - Y.w, dz = zi - Z.w;
        const float d2 = dx*dx + dy*dy + dz*dz;
        acc += (d2 <= tau) ? (W0 * fabsf(dx) + W1 * fabsf(dy) + W2 * fabsf(dz)) : 0.f;
      }
    }
  }

  // ---- reduce over the 8 slice lanes (contiguous within a wave) ----
  acc += __shfl_xor(acc, 1);
  acc += __shfl_xor(acc, 2);
  acc += __shfl_xor(acc, 4);
  if (sl == 0) {
    const float xw0 = W0 * xi + W1 * yi + W2 * zi;
    out[orig] = bias[0] + (xw0 * 8.778174593052022f + 0.5f * acc) * (1.0f / 12.0f);
  }
}

extern "C" void kernel_launch(void* const* d_in, const int* in_sizes, int n_in,
                              void* d_out, int out_size, void* d_ws, size_t ws_size,
                              hipStream_t stream) {
  const float* p  = (const float*)d_in[0];
  const float* W  = (const float*)d_in[1];
  const float* bb = (const float*)d_in[2];
  float* out = (float*)d_out;

  const int n = in_sizes[0] / 3;   // 16384

  int*    hist   = (int*)d_ws;
  int*    cursor = (int*)((char*)d_ws + NBINS * 4);
  float4* sorted = (float4*)((char*)d_ws + 2 * NBINS * 4);

  hipMemsetAsync(hist, 0, NBINS * 4, stream);

  const int b256 = (n + 255) / 256;
  hist_kernel<<<b256, 256, 0, stream>>>(p, hist, n);
  scan_kernel<<<1, 256, 0, stream>>>(hist, cursor);
  scatter_kernel<<<b256, 256, 0, stream>>>(p, cursor, sorted, n);
  query_kernel<<<n / QPB, 256, 0, stream>>>(sorted, W, bb, out, n);
}